// Round 2
// baseline (122.062 us; speedup 1.0000x reference)
//
#include <hip/hip_runtime.h>
#include <hip/hip_bf16.h>

// Problem: B=4, N=2048, C=512, H=8, D=64, L=64, SCALE=0.125. Inputs f32, output f32.
// No softmax => attention is linear => reassociate:
//   out[b] = (x[b]@Wq * SCALE)(2048x512) @ Wcat[b](512x64)
//   Wcat[b][h*64+d][:] = ( sum_m k[b,m,h,d] * v[m,h,:] ) @ proj_h

using f32x4 = __attribute__((ext_vector_type(4))) float;
using s16x8 = __attribute__((ext_vector_type(8))) short;  // 8 bf16 (4 VGPRs), MFMA operand

__device__ __forceinline__ unsigned short f2bf(float f) {
  unsigned int i;
  __builtin_memcpy(&i, &f, 4);
  unsigned int lsb = (i >> 16) & 1u;
  i += 0x7fffu + lsb;  // round-to-nearest-even
  return (unsigned short)(i >> 16);
}
__device__ __forceinline__ float bf2f(unsigned short u) {
  unsigned int i = ((unsigned int)u) << 16;
  float f;
  __builtin_memcpy(&f, &i, 4);
  return f;
}
__device__ __forceinline__ void async_cp16(const void* g, void* l) {
  // 16B-wide global->LDS DMA; LDS dest is wave-uniform base + lane*16
  __builtin_amdgcn_global_load_lds((const __attribute__((address_space(1))) void*)g,
                                   (__attribute__((address_space(3))) void*)l, 16, 0, 0);
}

// ---------------- 0) convert x f32 -> bf16 (4*2048*512 elements)
__global__ void k_convert_x(const float* __restrict__ x, unsigned short* __restrict__ xb) {
  size_t i = ((size_t)blockIdx.x * 256 + threadIdx.x) * 8;
  f32x4 a = *(const f32x4*)(x + i);
  f32x4 b = *(const f32x4*)(x + i + 4);
  ushort4 lo, hi;
  lo.x = f2bf(a[0]); lo.y = f2bf(a[1]); lo.z = f2bf(a[2]); lo.w = f2bf(a[3]);
  hi.x = f2bf(b[0]); hi.y = f2bf(b[1]); hi.z = f2bf(b[2]); hi.w = f2bf(b[3]);
  *(ushort4*)(xb + i) = lo;
  *(ushort4*)(xb + i + 4) = hi;
}

// ---------------- 1) transpose+remap+convert qkv: qkvT[s*512+h*64+d][c] = qkv[c][h*128+s*64+d]
__global__ void k_transpose_qkv(const float* __restrict__ qkv,
                                unsigned short* __restrict__ qkvT) {
  __shared__ float tile[32][33];
  int j0 = blockIdx.x * 32;   // col block of qkv (stays within one (h,s) 64-block)
  int c0 = blockIdx.y * 32;
  int tx = threadIdx.x, ty = threadIdx.y;  // 32 x 8
#pragma unroll
  for (int i = 0; i < 32; i += 8)
    tile[ty + i][tx] = qkv[(size_t)(c0 + ty + i) * 1024 + j0 + tx];
  __syncthreads();
  int h = j0 >> 7, s = (j0 >> 6) & 1, d0 = j0 & 63;
  int jp0 = s * 512 + h * 64 + d0;
#pragma unroll
  for (int i = 0; i < 32; i += 8)
    qkvT[(size_t)(jp0 + ty + i) * 512 + c0 + tx] = f2bf(tile[tx][ty + i]);
}

// ---------------- 2) GEMM1: h = xb(8192x512) @ qkvT^T(512x1024) -> split Q (scaled), K
__global__ void k_gemm1(const unsigned short* __restrict__ A,   // xb [8192][512] bf16
                        const unsigned short* __restrict__ Bt,  // qkvT [1024][512] bf16
                        unsigned short* __restrict__ Qws,       // [8192][512] col = h*64+d
                        unsigned short* __restrict__ Kws) {     // [8192][512]
  __shared__ unsigned short As[128 * 64];
  __shared__ unsigned short Bs[128 * 64];
  const int m0 = blockIdx.x * 128;
  const int n0 = blockIdx.y * 128;
  const int tid = threadIdx.x;
  const int lane = tid & 63;
  const int wave = tid >> 6;       // 4 waves
  const int wm = wave >> 1, wn = wave & 1;

  f32x4 acc[4][4] = {};

  const int rstage = wave * 32 + (lane >> 3);
  const int cstage = (lane & 7) * 8;

  for (int kt = 0; kt < 512; kt += 64) {
    __syncthreads();
#pragma unroll
    for (int i = 0; i < 4; ++i) {
      async_cp16(A + (size_t)(m0 + rstage + i * 8) * 512 + kt + cstage,
                 As + (wave * 32 + i * 8) * 64);
      async_cp16(Bt + (size_t)(n0 + rstage + i * 8) * 512 + kt + cstage,
                 Bs + (wave * 32 + i * 8) * 64);
    }
    __syncthreads();
#pragma unroll
    for (int kk = 0; kk < 64; kk += 32) {
      s16x8 af[4], bfr[4];
#pragma unroll
      for (int i = 0; i < 4; ++i)
        af[i] = *(const s16x8*)(As + (wm * 64 + i * 16 + (lane & 15)) * 64 + kk + (lane >> 4) * 8);
#pragma unroll
      for (int j = 0; j < 4; ++j)
        bfr[j] = *(const s16x8*)(Bs + (wn * 64 + j * 16 + (lane & 15)) * 64 + kk + (lane >> 4) * 8);
#pragma unroll
      for (int i = 0; i < 4; ++i)
#pragma unroll
        for (int j = 0; j < 4; ++j)
          acc[i][j] = __builtin_amdgcn_mfma_f32_16x16x32_bf16(af[i], bfr[j], acc[i][j], 0, 0, 0);
    }
  }
  const int n_base = n0 + wn * 64;
#pragma unroll
  for (int i = 0; i < 4; ++i) {
    int grow = m0 + wm * 64 + i * 16 + (lane >> 4) * 4;
#pragma unroll
    for (int j = 0; j < 4; ++j) {
      int gcol = n_base + j * 16 + (lane & 15);
      unsigned short* dst;
      float scale;
      if (gcol < 512) { dst = Qws; scale = 0.125f; }        // q, fold SCALE (exact pow2)
      else            { dst = Kws; gcol -= 512; scale = 1.0f; }
#pragma unroll
      for (int r = 0; r < 4; ++r)
        dst[(size_t)(grow + r) * 512 + gcol] = f2bf(acc[i][j][r] * scale);
    }
  }
}

// ---------------- 3) KV partials: KVp[b][h][chunk][dq][l] = sum_{n in chunk} k*v  (f32)
__global__ void k_kv_partial(const unsigned short* __restrict__ Kws,
                             const float* __restrict__ v,   // [2048][512] f32, col h*64+l
                             float* __restrict__ KVp) {
  const int wg = blockIdx.x;      // b*128 + h*16 + chunk
  const int chunk = wg & 15;
  const int h = (wg >> 4) & 7;
  const int b = wg >> 7;
  __shared__ unsigned short Ks[128 * 64];  // 16 KB bf16
  __shared__ float Vs[128 * 64];           // 32 KB f32
  const int tid = threadIdx.x;
  const int lane = tid & 63;
  const int wave = tid >> 6;
  const int n0 = chunk * 128;
  // K staging: 8 lanes/row (16B = 8 bf16), 8 rows/call, 4 calls -> 32 rows/wave
  {
    const int r = wave * 32 + (lane >> 3);
    const int c = (lane & 7) * 8;
#pragma unroll
    for (int i = 0; i < 4; ++i)
      async_cp16(Kws + (size_t)(b * 2048 + n0 + r + i * 8) * 512 + h * 64 + c,
                 Ks + (wave * 32 + i * 8) * 64);
  }
  // V staging (f32): 16 lanes/row (16B = 4 f32), 4 rows/call, 8 calls -> 32 rows/wave
  {
    const int r = wave * 32 + (lane >> 4);
    const int c = (lane & 15) * 4;
#pragma unroll
    for (int i = 0; i < 8; ++i)
      async_cp16(v + (size_t)(n0 + r + i * 4) * 512 + h * 64 + c,
                 Vs + (wave * 32 + i * 4) * 64);
  }
  __syncthreads();
  const int dq0 = (tid & 15) * 4;
  const int l0 = (tid >> 4) * 4;
  float acc[4][4] = {};
#pragma unroll 4
  for (int n = 0; n < 128; ++n) {
    ushort4 ku = *(const ushort4*)(Ks + n * 64 + dq0);
    f32x4 va = *(const f32x4*)(Vs + n * 64 + l0);
    float ka[4] = {bf2f(ku.x), bf2f(ku.y), bf2f(ku.z), bf2f(ku.w)};
#pragma unroll
    for (int a = 0; a < 4; ++a)
#pragma unroll
      for (int c = 0; c < 4; ++c)
        acc[a][c] += ka[a] * va[c];
  }
  float* dst = KVp + (size_t)wg * 4096;
#pragma unroll
  for (int a = 0; a < 4; ++a) {
    f32x4 o;
    o[0] = acc[a][0]; o[1] = acc[a][1]; o[2] = acc[a][2]; o[3] = acc[a][3];
    *(f32x4*)(dst + (dq0 + a) * 64 + l0) = o;
  }
}

// ---------------- 4) reduce partials + W = KV@proj_h -> WcatT[b][dout][h*64+dq] (bf16)
__global__ void k_kv_reduce_w(const float* __restrict__ KVp,
                              const float* __restrict__ proj,   // [512][64] f32
                              unsigned short* __restrict__ WcatT) {  // [B][64][512]
  const int bh = blockIdx.x;  // b*8 + h
  const int h = bh & 7;
  const int b = bh >> 3;
  __shared__ float kv[64 * 65];   // padded: conflict-free column reads
  __shared__ float pj[64 * 64];
  const int tid = threadIdx.x;
#pragma unroll
  for (int j = 0; j < 16; ++j) {
    int e = tid + j * 256;
    float s = 0.f;
#pragma unroll
    for (int c = 0; c < 16; ++c)
      s += KVp[((size_t)bh * 16 + c) * 4096 + e];
    kv[(e >> 6) * 65 + (e & 63)] = s;
  }
#pragma unroll
  for (int j = 0; j < 16; ++j) {
    int e = tid + j * 256;
    pj[e] = proj[(size_t)(h * 64 + (e >> 6)) * 64 + (e & 63)];
  }
  __syncthreads();
  const int dq = tid >> 2;
  const int d0 = (tid & 3) * 16;
  f32x4 w[4] = {};
  for (int l = 0; l < 64; ++l) {
    float kvv = kv[dq * 65 + l];
#pragma unroll
    for (int jj = 0; jj < 4; ++jj) {
      f32x4 p4 = *(const f32x4*)(pj + l * 64 + d0 + jj * 4);
      w[jj] += kvv * p4;
    }
  }
#pragma unroll
  for (int jj = 0; jj < 4; ++jj)
#pragma unroll
    for (int q = 0; q < 4; ++q)
      WcatT[(size_t)(b * 64 + d0 + jj * 4 + q) * 512 + h * 64 + dq] = f2bf(w[jj][q]);
}

// ---------------- 5) GEMM2: out[b] = Qws[b](2048x512) @ WcatT[b]^T(512x64), f32 out
__global__ void k_gemm2(const unsigned short* __restrict__ Qws,
                        const unsigned short* __restrict__ WcatT,
                        float* __restrict__ out) {   // [8192][64] f32
  const int mt = blockIdx.x;  // 0..15
  const int b = blockIdx.y;   // 0..3
  const int m0 = b * 2048 + mt * 128;
  __shared__ unsigned short As[128 * 64];
  __shared__ unsigned short Bs[64 * 64];
  const int tid = threadIdx.x;
  const int lane = tid & 63;
  const int wave = tid >> 6;
  const int rstage = wave * 32 + (lane >> 3);
  const int cstage = (lane & 7) * 8;
  f32x4 acc[2][4] = {};
  const unsigned short* Bb = WcatT + (size_t)b * 64 * 512;
  for (int kt = 0; kt < 512; kt += 64) {
    __syncthreads();
#pragma unroll
    for (int i = 0; i < 4; ++i)
      async_cp16(Qws + (size_t)(m0 + rstage + i * 8) * 512 + kt + cstage,
                 As + (wave * 32 + i * 8) * 64);
#pragma unroll
    for (int i = 0; i < 2; ++i)
      async_cp16(Bb + (size_t)(wave * 16 + i * 8 + (lane >> 3)) * 512 + kt + cstage,
                 Bs + (wave * 16 + i * 8) * 64);
    __syncthreads();
#pragma unroll
    for (int kk = 0; kk < 64; kk += 32) {
      s16x8 af[2], bfr[4];
#pragma unroll
      for (int i = 0; i < 2; ++i)
        af[i] = *(const s16x8*)(As + (wave * 32 + i * 16 + (lane & 15)) * 64 + kk + (lane >> 4) * 8);
#pragma unroll
      for (int j = 0; j < 4; ++j)
        bfr[j] = *(const s16x8*)(Bs + (j * 16 + (lane & 15)) * 64 + kk + (lane >> 4) * 8);
#pragma unroll
      for (int i = 0; i < 2; ++i)
#pragma unroll
        for (int j = 0; j < 4; ++j)
          acc[i][j] = __builtin_amdgcn_mfma_f32_16x16x32_bf16(af[i], bfr[j], acc[i][j], 0, 0, 0);
    }
  }
#pragma unroll
  for (int i = 0; i < 2; ++i) {
    int grow = m0 + wave * 32 + i * 16 + (lane >> 4) * 4;
#pragma unroll
    for (int j = 0; j < 4; ++j) {
      int gcol = j * 16 + (lane & 15);
#pragma unroll
      for (int r = 0; r < 4; ++r)
        out[(size_t)(grow + r) * 64 + gcol] = acc[i][j][r];
    }
  }
}

extern "C" void kernel_launch(void* const* d_in, const int* in_sizes, int n_in,
                              void* d_out, int out_size, void* d_ws, size_t ws_size,
                              hipStream_t stream) {
  const float* x    = (const float*)d_in[0];  // [4][2048][512] f32
  const float* v    = (const float*)d_in[1];  // [2048][8][64]  f32
  const float* qkv  = (const float*)d_in[2];  // [512][1024]    f32
  const float* proj = (const float*)d_in[3];  // [512][64]      f32
  float* out = (float*)d_out;                 // [4][2048][64]  f32

  char* ws = (char*)d_ws;
  unsigned short* xb   = (unsigned short*)ws; ws += (size_t)8192 * 512 * 2;  // 8.4 MB
  unsigned short* qkvT = (unsigned short*)ws; ws += (size_t)1024 * 512 * 2;  // 1 MB
  unsigned short* Qws  = (unsigned short*)ws; ws += (size_t)8192 * 512 * 2;  // 8.4 MB
  unsigned short* Kws  = (unsigned short*)ws; ws += (size_t)8192 * 512 * 2;  // 8.4 MB
  float*          KVp  = (float*)ws;          ws += (size_t)512 * 4096 * 4;  // 8.4 MB
  unsigned short* Wc   = (unsigned short*)ws; ws += (size_t)4 * 64 * 512 * 2;

  hipLaunchKernelGGL(k_convert_x, dim3(2048), dim3(256), 0, stream, x, xb);
  hipLaunchKernelGGL(k_transpose_qkv, dim3(32, 16), dim3(32, 8), 0, stream, qkv, qkvT);
  hipLaunchKernelGGL(k_gemm1, dim3(64, 8), dim3(256), 0, stream, xb, qkvT, Qws, Kws);
  hipLaunchKernelGGL(k_kv_partial, dim3(512), dim3(256), 0, stream, Kws, v, KVp);
  hipLaunchKernelGGL(k_kv_reduce_w, dim3(32), dim3(256), 0, stream, KVp, proj, Wc);
  hipLaunchKernelGGL(k_gemm2, dim3(16, 4), dim3(256), 0, stream, Qws, Wc, out);
}

// Round 3
// 118.710 us; speedup vs baseline: 1.0282x; 1.0282x over previous
//
#include <hip/hip_runtime.h>
#include <hip/hip_bf16.h>

// Problem: B=4, N=2048, C=512, H=8, D=64, L=64, SCALE=0.125. Inputs f32, output f32.
// No softmax => attention is linear => reassociate:
//   out[b] = (x[b]@Wq * SCALE)(2048x512) @ Wcat[b](512x64)
//   Wcat[b][h*64+d][:] = ( sum_m k[b,m,h,d] * v[m,h,:] ) @ proj_h

using f32x4 = __attribute__((ext_vector_type(4))) float;
using s16x8 = __attribute__((ext_vector_type(8))) short;  // 8 bf16 (4 VGPRs), MFMA operand

__device__ __forceinline__ unsigned short f2bf(float f) {
  unsigned int i;
  __builtin_memcpy(&i, &f, 4);
  unsigned int lsb = (i >> 16) & 1u;
  i += 0x7fffu + lsb;  // round-to-nearest-even
  return (unsigned short)(i >> 16);
}
__device__ __forceinline__ float bf2f(unsigned short u) {
  unsigned int i = ((unsigned int)u) << 16;
  float f;
  __builtin_memcpy(&f, &i, 4);
  return f;
}
__device__ __forceinline__ void async_cp16(const void* g, void* l) {
  // 16B global->LDS DMA; LDS dest must be WAVE-UNIFORM base (HW adds lane*16)
  __builtin_amdgcn_global_load_lds((const __attribute__((address_space(1))) void*)g,
                                   (__attribute__((address_space(3))) void*)l, 16, 0, 0);
}

// ---------------- 1) prep: convert x f32->bf16 (blocks 0..2047), transpose qkv (blocks 2048..2559)
__global__ void k_prep(const float* __restrict__ x, const float* __restrict__ qkv,
                       unsigned short* __restrict__ xb, unsigned short* __restrict__ qkvT) {
  const int id = blockIdx.x;
  const int tid = threadIdx.x;
  if (id < 2048) {
    size_t i = ((size_t)id * 256 + tid) * 8;
    f32x4 a = *(const f32x4*)(x + i);
    f32x4 b = *(const f32x4*)(x + i + 4);
    ushort4 lo, hi;
    lo.x = f2bf(a[0]); lo.y = f2bf(a[1]); lo.z = f2bf(a[2]); lo.w = f2bf(a[3]);
    hi.x = f2bf(b[0]); hi.y = f2bf(b[1]); hi.z = f2bf(b[2]); hi.w = f2bf(b[3]);
    *(ushort4*)(xb + i) = lo;
    *(ushort4*)(xb + i + 4) = hi;
  } else {
    // qkvT[s*512+h*64+d][c] = qkv[c][h*128+s*64+d]
    __shared__ float tile[32][33];
    const int idx = id - 2048;
    const int j0 = (idx & 31) * 32;
    const int c0 = (idx >> 5) * 32;
    const int tx = tid & 31, ty = tid >> 5;  // 32 x 8
#pragma unroll
    for (int i = 0; i < 32; i += 8)
      tile[ty + i][tx] = qkv[(size_t)(c0 + ty + i) * 1024 + j0 + tx];
    __syncthreads();
    const int h = j0 >> 7, s = (j0 >> 6) & 1, d0 = j0 & 63;
    const int jp0 = s * 512 + h * 64 + d0;
#pragma unroll
    for (int i = 0; i < 32; i += 8)
      qkvT[(size_t)(jp0 + ty + i) * 512 + c0 + tx] = f2bf(tile[tx][ty + i]);
  }
}

// ---------------- 2) GEMM1 (8 waves): h = xb(8192x512) @ qkvT^T(512x1024) -> Q (scaled), K
__global__ __launch_bounds__(512) void k_gemm1(
    const unsigned short* __restrict__ A,   // xb [8192][512] bf16
    const unsigned short* __restrict__ Bt,  // qkvT [1024][512] bf16
    unsigned short* __restrict__ Qws,       // [8192][512] col = h*64+d
    unsigned short* __restrict__ Kws) {     // [8192][512]
  __shared__ unsigned short As[128 * 64];
  __shared__ unsigned short Bs[128 * 64];
  const int m0 = blockIdx.x * 128;
  const int n0 = blockIdx.y * 128;
  const int tid = threadIdx.x;
  const int lane = tid & 63;
  const int wave = tid >> 6;       // 8 waves: wm 4 x wn 2
  const int wm = wave >> 1, wn = wave & 1;

  f32x4 acc[2][4] = {};

  const int rlane = lane >> 3;        // 0..7 rows within wave's 8-row stage group
  const int clane = (lane & 7) * 8;   // 8 bf16 = 16B

  for (int kt = 0; kt < 512; kt += 64) {
    __syncthreads();
    // 512 threads x 16B = 8KB = 64 rows/call; 2 calls for A (128 rows), 2 for B
#pragma unroll
    for (int i = 0; i < 2; ++i) {
      async_cp16(A + (size_t)(m0 + i * 64 + wave * 8 + rlane) * 512 + kt + clane,
                 As + (i * 64 + wave * 8) * 64);
      async_cp16(Bt + (size_t)(n0 + i * 64 + wave * 8 + rlane) * 512 + kt + clane,
                 Bs + (i * 64 + wave * 8) * 64);
    }
    __syncthreads();
#pragma unroll
    for (int kk = 0; kk < 64; kk += 32) {
      s16x8 af[2], bfr[4];
#pragma unroll
      for (int i = 0; i < 2; ++i)
        af[i] = *(const s16x8*)(As + (wm * 32 + i * 16 + (lane & 15)) * 64 + kk + (lane >> 4) * 8);
#pragma unroll
      for (int j = 0; j < 4; ++j)
        bfr[j] = *(const s16x8*)(Bs + (wn * 64 + j * 16 + (lane & 15)) * 64 + kk + (lane >> 4) * 8);
#pragma unroll
      for (int i = 0; i < 2; ++i)
#pragma unroll
        for (int j = 0; j < 4; ++j)
          acc[i][j] = __builtin_amdgcn_mfma_f32_16x16x32_bf16(af[i], bfr[j], acc[i][j], 0, 0, 0);
    }
  }
  const int n_base = n0 + wn * 64;
#pragma unroll
  for (int i = 0; i < 2; ++i) {
    int grow = m0 + wm * 32 + i * 16 + (lane >> 4) * 4;
#pragma unroll
    for (int j = 0; j < 4; ++j) {
      int gcol = n_base + j * 16 + (lane & 15);
      unsigned short* dst;
      float scale;
      if (gcol < 512) { dst = Qws; scale = 0.125f; }        // q, fold SCALE (exact pow2)
      else            { dst = Kws; gcol -= 512; scale = 1.0f; }
#pragma unroll
      for (int r = 0; r < 4; ++r)
        dst[(size_t)(grow + r) * 512 + gcol] = f2bf(acc[i][j][r] * scale);
    }
  }
}

// ---------------- 3) KV partials: KVp[b][h][chunk][dq][l] = sum_{n in chunk} k*v  (f32)
__global__ void k_kv_partial(const unsigned short* __restrict__ Kws,
                             const float* __restrict__ v,   // [2048][512] f32, col h*64+l
                             float* __restrict__ KVp) {
  const int wg = blockIdx.x;      // b*128 + h*16 + chunk
  const int chunk = wg & 15;
  const int h = (wg >> 4) & 7;
  const int b = wg >> 7;
  __shared__ unsigned short Ks[128 * 64];  // 16 KB bf16
  __shared__ float Vs[128 * 64];           // 32 KB f32
  const int tid = threadIdx.x;
  const int lane = tid & 63;
  const int wave = tid >> 6;
  const int n0 = chunk * 128;
  // K staging: 8 lanes/row (16B = 8 bf16), 8 rows/call, 4 calls -> 32 rows/wave
  {
    const int r = wave * 32 + (lane >> 3);
    const int c = (lane & 7) * 8;
#pragma unroll
    for (int i = 0; i < 4; ++i)
      async_cp16(Kws + (size_t)(b * 2048 + n0 + r + i * 8) * 512 + h * 64 + c,
                 Ks + (wave * 32 + i * 8) * 64);
  }
  // V staging (f32): 16 lanes/row (16B = 4 f32), 4 rows/call, 8 calls -> 32 rows/wave
  {
    const int r = wave * 32 + (lane >> 4);
    const int c = (lane & 15) * 4;
#pragma unroll
    for (int i = 0; i < 8; ++i)
      async_cp16(v + (size_t)(n0 + r + i * 4) * 512 + h * 64 + c,
                 Vs + (wave * 32 + i * 4) * 64);
  }
  __syncthreads();
  const int dq0 = (tid & 15) * 4;
  const int l0 = (tid >> 4) * 4;
  float acc[4][4] = {};
#pragma unroll 4
  for (int n = 0; n < 128; ++n) {
    ushort4 ku = *(const ushort4*)(Ks + n * 64 + dq0);
    f32x4 va = *(const f32x4*)(Vs + n * 64 + l0);
    float ka[4] = {bf2f(ku.x), bf2f(ku.y), bf2f(ku.z), bf2f(ku.w)};
#pragma unroll
    for (int a = 0; a < 4; ++a)
#pragma unroll
      for (int c = 0; c < 4; ++c)
        acc[a][c] += ka[a] * va[c];
  }
  float* dst = KVp + (size_t)wg * 4096;
#pragma unroll
  for (int a = 0; a < 4; ++a) {
    f32x4 o;
    o[0] = acc[a][0]; o[1] = acc[a][1]; o[2] = acc[a][2]; o[3] = acc[a][3];
    *(f32x4*)(dst + (dq0 + a) * 64 + l0) = o;
  }
}

// ---------------- 4) reduce partials + W = KV@proj_h -> WcatT[b][dout][h*64+dq] (bf16)
__global__ void k_kv_reduce_w(const float* __restrict__ KVp,
                              const float* __restrict__ proj,   // [512][64] f32
                              unsigned short* __restrict__ WcatT) {  // [B][64][512]
  const int bh = blockIdx.x;  // b*8 + h
  const int h = bh & 7;
  const int b = bh >> 3;
  __shared__ float kv[64 * 65];   // padded: conflict-free column reads
  __shared__ float pj[64 * 64];
  const int tid = threadIdx.x;
#pragma unroll
  for (int j = 0; j < 16; ++j) {
    int e = tid + j * 256;
    float s = 0.f;
#pragma unroll
    for (int c = 0; c < 16; ++c)
      s += KVp[((size_t)bh * 16 + c) * 4096 + e];
    kv[(e >> 6) * 65 + (e & 63)] = s;
  }
#pragma unroll
  for (int j = 0; j < 16; ++j) {
    int e = tid + j * 256;
    pj[e] = proj[(size_t)(h * 64 + (e >> 6)) * 64 + (e & 63)];
  }
  __syncthreads();
  const int dq = tid >> 2;
  const int d0 = (tid & 3) * 16;
  f32x4 w[4] = {};
  for (int l = 0; l < 64; ++l) {
    float kvv = kv[dq * 65 + l];
#pragma unroll
    for (int jj = 0; jj < 4; ++jj) {
      f32x4 p4 = *(const f32x4*)(pj + l * 64 + d0 + jj * 4);
      w[jj] += kvv * p4;
    }
  }
#pragma unroll
  for (int jj = 0; jj < 4; ++jj)
#pragma unroll
    for (int q = 0; q < 4; ++q)
      WcatT[(size_t)(b * 64 + d0 + jj * 4 + q) * 512 + h * 64 + dq] = f2bf(w[jj][q]);
}

// ---------------- 5) GEMM2 streaming: out[b] = Qws[b](2048x512) @ WcatT[b]^T(512x64)
// 512 blocks x 1 wave; 16-row m-tile per wave; no LDS, no barriers. All operands L2-hot.
__global__ __launch_bounds__(64) void k_gemm2(
    const unsigned short* __restrict__ Qws,
    const unsigned short* __restrict__ WcatT,
    float* __restrict__ out) {   // [8192][64] f32
  const int m0 = blockIdx.x * 16;
  const int lane = threadIdx.x;
  const unsigned short* Bb = WcatT + (size_t)(m0 >> 11) * 64 * 512;
  const int arow = lane & 15;
  const int koff = (lane >> 4) * 8;
  f32x4 acc[4] = {};
#pragma unroll
  for (int kk = 0; kk < 16; ++kk) {
    s16x8 af = *(const s16x8*)(Qws + (size_t)(m0 + arow) * 512 + kk * 32 + koff);
#pragma unroll
    for (int j = 0; j < 4; ++j) {
      s16x8 bf = *(const s16x8*)(Bb + (size_t)(j * 16 + arow) * 512 + kk * 32 + koff);
      acc[j] = __builtin_amdgcn_mfma_f32_16x16x32_bf16(af, bf, acc[j], 0, 0, 0);
    }
  }
  const int grow = m0 + (lane >> 4) * 4;
#pragma unroll
  for (int j = 0; j < 4; ++j) {
    int gcol = j * 16 + arow;
#pragma unroll
    for (int r = 0; r < 4; ++r)
      out[(size_t)(grow + r) * 64 + gcol] = acc[j][r];
  }
}

extern "C" void kernel_launch(void* const* d_in, const int* in_sizes, int n_in,
                              void* d_out, int out_size, void* d_ws, size_t ws_size,
                              hipStream_t stream) {
  const float* x    = (const float*)d_in[0];  // [4][2048][512] f32
  const float* v    = (const float*)d_in[1];  // [2048][8][64]  f32
  const float* qkv  = (const float*)d_in[2];  // [512][1024]    f32
  const float* proj = (const float*)d_in[3];  // [512][64]      f32
  float* out = (float*)d_out;                 // [4][2048][64]  f32

  char* ws = (char*)d_ws;
  unsigned short* xb   = (unsigned short*)ws; ws += (size_t)8192 * 512 * 2;  // 8.4 MB
  unsigned short* qkvT = (unsigned short*)ws; ws += (size_t)1024 * 512 * 2;  // 1 MB
  unsigned short* Qws  = (unsigned short*)ws; ws += (size_t)8192 * 512 * 2;  // 8.4 MB
  unsigned short* Kws  = (unsigned short*)ws; ws += (size_t)8192 * 512 * 2;  // 8.4 MB
  float*          KVp  = (float*)ws;          ws += (size_t)512 * 4096 * 4;  // 8.4 MB
  unsigned short* Wc   = (unsigned short*)ws; ws += (size_t)4 * 64 * 512 * 2;

  hipLaunchKernelGGL(k_prep, dim3(2560), dim3(256), 0, stream, x, qkv, xb, qkvT);
  hipLaunchKernelGGL(k_gemm1, dim3(64, 8), dim3(512), 0, stream, xb, qkvT, Qws, Kws);
  hipLaunchKernelGGL(k_kv_partial, dim3(512), dim3(256), 0, stream, Kws, v, KVp);
  hipLaunchKernelGGL(k_kv_reduce_w, dim3(32), dim3(256), 0, stream, KVp, proj, Wc);
  hipLaunchKernelGGL(k_gemm2, dim3(512), dim3(64), 0, stream, Qws, Wc, out);
}